// Round 13
// baseline (833.241 us; speedup 1.0000x reference)
//
#include <hip/hip_runtime.h>
#include <hip/hip_fp16.h>
#include <math.h>

// Problem constants (fixed by setup_inputs)
#define DM    256
#define LQ    11253
#define NTOK  (2*LQ)        // 22506
#define TT2   32            // tokens per block (GEMM kernels)
#define NBLK32 704          // ceil(NTOK/32)
#define AS    264           // ushorts per A (bf16) LDS row: 256 + 8 pad
#define CS    260           // floats per C (fp32) LDS row: 256 + 4 pad
#define AWS   132           // floats per AW row: 128 + 4 pad

typedef __attribute__((ext_vector_type(8))) short bf16x8;
typedef __attribute__((ext_vector_type(4))) float f32x4;

// packed-weight offsets (ushort units)
#define PW_DS  0
#define PW_VAL 65536
#define PW_OFA 131072      // w_off (nt 0..15) ++ w_attn (nt 16..23), 98304 ushorts
#define PW_W1  229376
#define PW_OC  294912      // w_out @ w_cs fused
// ws layout (bytes): pw [0,~721K) | b_oc [860160,861184) | xy [1MiB,12MiB) | aw [12MiB,~17.8MiB)
#define B_OC_OFF  860160u
#define XY_WS_OFF (1u<<20)
#define AW_WS_OFF (12u<<20)
// d_out layout: per token a 1024B slot: ATT bf16 [0,512) | value bf16 [512,1024)

// ---------------- small helpers ----------------

__device__ __forceinline__ ushort f2b(float x) {   // fp32 -> bf16 (RNE)
  union { float f; unsigned u; } c; c.f = x;
  unsigned u = c.u + 0x7fffu + ((c.u >> 16) & 1u);
  return (ushort)(u >> 16);
}
__device__ __forceinline__ float blo(unsigned u) {
  union { unsigned u; float f; } c; c.u = u << 16; return c.f;
}
__device__ __forceinline__ float bhi(unsigned u) {
  union { unsigned u; float f; } c; c.u = u & 0xffff0000u; return c.f;
}
__device__ __forceinline__ int clampr(int v) { return min(max(v, 0), NTOK - 1); }

// ------------- k_prep: weight pack (144 blk) + w_oc matmul (64) + b_oc (1) --

__global__ __launch_bounds__(256) void k_prep(
    const float* __restrict__ w_ds, const float* __restrict__ w_val,
    const float* __restrict__ w_off, const float* __restrict__ w1,
    const float* __restrict__ wa,
    const float* __restrict__ w_out, const float* __restrict__ w_cs,
    const float* __restrict__ b_out, const float* __restrict__ b_cs,
    ushort* __restrict__ pw, float* __restrict__ b_oc) {
  __shared__ float rows[4][256];
  const int bid = blockIdx.x, j = threadIdx.x;

  if (bid < 144) {
    // ---- pack role: fp32 [K][N] -> bf16 MFMA B-fragments ----
    const int gid = bid * 256 + j;
    const float* W; int N; size_t obase; int local; int ntAdd;
    if (gid < 4 * 8192) {
      const int wi = gid >> 13; local = gid & 8191; N = 256; ntAdd = 0;
      obase = (wi == 0) ? PW_DS : (wi == 1) ? PW_VAL : (wi == 2) ? PW_OFA : PW_W1;
      W = (wi == 0) ? w_ds : (wi == 1) ? w_val : (wi == 2) ? w_off : w1;
    } else {
      local = gid - 32768; N = 128; obase = PW_OFA; W = wa; ntAdd = 16;
    }
    const int l = local & 63, f = local >> 6;
    const int kt = f & 7, nt = f >> 3;
    const int k0 = kt * 32 + (l >> 4) * 8, col = nt * 16 + (l & 15);
    ushort v[8];
#pragma unroll
    for (int e = 0; e < 8; ++e) v[e] = f2b(W[(size_t)(k0 + e) * N + col]);
    const size_t fout = (size_t)(((nt + ntAdd) * 8 + kt) * 64 + l);
    *reinterpret_cast<uint4*>(&pw[obase + fout * 8]) =
        *reinterpret_cast<const uint4*>(v);
  } else if (bid < 208) {
    // ---- oc matmul role: w_oc = w_out @ w_cs, 4 K-rows per block ----
    const int k0 = (bid - 144) * 4;
#pragma unroll
    for (int rr = 0; rr < 4; ++rr) rows[rr][j] = w_out[(size_t)(k0 + rr) * 256 + j];
    __syncthreads();
    float s[4];
#pragma unroll
    for (int rr = 0; rr < 4; ++rr) s[rr] = 0.f;
    for (int m = 0; m < 256; ++m) {
      const float c = w_cs[(size_t)m * 256 + j];
#pragma unroll
      for (int rr = 0; rr < 4; ++rr) s[rr] = fmaf(rows[rr][m], c, s[rr]);
    }
    const int nt = j >> 4;
#pragma unroll
    for (int rr = 0; rr < 4; ++rr) {
      const int k = k0 + rr;
      const int kt = k >> 5, ln = ((k >> 3) & 3) * 16 + (j & 15), e = k & 7;
      pw[PW_OC + ((size_t)((nt * 8 + kt) * 64 + ln)) * 8 + e] = f2b(s[rr]);
    }
  } else {
    // ---- b_oc role ----
    float s = b_cs[j];
    for (int m = 0; m < 256; ++m) s = fmaf(b_out[m], w_cs[(size_t)m * 256 + j], s);
    b_oc[j] = s;
  }
}

// -------- GEMM tile helpers: 512 threads, 8 waves, 32 tokens, B reused x2 ---

template<int NTW>
__device__ __forceinline__ void gemm_tile32(const ushort* __restrict__ A,
                                            const ushort* __restrict__ Bp,
                                            int ntBase, int lane,
                                            f32x4 (&acc)[2][NTW]) {
  const int r = lane & 15, hk = lane >> 4;
  const ushort* arow0 = A + r * AS + hk * 8;
  const ushort* arow1 = A + (r + 16) * AS + hk * 8;
#pragma unroll
  for (int m = 0; m < 2; ++m)
#pragma unroll
    for (int nt = 0; nt < NTW; ++nt) acc[m][nt] = (f32x4){0.f, 0.f, 0.f, 0.f};
#pragma unroll
  for (int kt = 0; kt < 8; ++kt) {
    const bf16x8 a0 = *(const bf16x8*)(arow0 + kt * 32);
    const bf16x8 a1 = *(const bf16x8*)(arow1 + kt * 32);
#pragma unroll
    for (int nt = 0; nt < NTW; ++nt) {
      const bf16x8 b = *(const bf16x8*)(Bp + ((size_t)((ntBase + nt) * 8 + kt) * 64 + lane) * 8);
      acc[0][nt] = __builtin_amdgcn_mfma_f32_16x16x32_bf16(a0, b, acc[0][nt], 0, 0, 0);
      acc[1][nt] = __builtin_amdgcn_mfma_f32_16x16x32_bf16(a1, b, acc[1][nt], 0, 0, 0);
    }
  }
}

template<int NTW>
__device__ __forceinline__ void acc_to_c32(const f32x4 (&acc)[2][NTW], float* C,
                                           const float* __restrict__ bias,
                                           int ntBase, int lane, int rowStride) {
  const int col = lane & 15, rb = (lane >> 4) * 4;
#pragma unroll
  for (int m = 0; m < 2; ++m)
#pragma unroll
    for (int nt = 0; nt < NTW; ++nt) {
      const int dim = (ntBase + nt) * 16 + col;
      const float bj = bias[dim];
#pragma unroll
      for (int i = 0; i < 4; ++i)
        C[(m * 16 + rb + i) * rowStride + dim] = acc[m][nt][i] + bj;
    }
}

// 8 waves x 4 rows each = 32 rows
template<bool ADD>
__device__ __forceinline__ void load_to_A32(const float* __restrict__ X,
                                            const float* __restrict__ Y,
                                            int tok0, ushort* A, int w, int lane) {
#pragma unroll
  for (int tt = 0; tt < 4; ++tt) {
    const int t = w * 4 + tt, tok = tok0 + t;
    float4 v = make_float4(0.f, 0.f, 0.f, 0.f);
    if (tok < NTOK) {
      v = *reinterpret_cast<const float4*>(&X[(size_t)tok * DM + lane * 4]);
      if (ADD) {
        const float4 y = *reinterpret_cast<const float4*>(&Y[(size_t)tok * DM + lane * 4]);
        v.x += y.x; v.y += y.y; v.z += y.z; v.w += y.w;
      }
    }
    ushort4 b; b.x = f2b(v.x); b.y = f2b(v.y); b.z = f2b(v.z); b.w = f2b(v.w);
    *reinterpret_cast<ushort4*>(&A[t * AS + lane * 4]) = b;
  }
}

// LayerNorm rows of C -> bf16 into A; 8 waves x 4 rows each
__device__ __forceinline__ void ln_c_to_a32(float* C, ushort* A,
                                            const float* __restrict__ g,
                                            const float* __restrict__ be,
                                            int w, int lane) {
#pragma unroll
  for (int tt = 0; tt < 4; ++tt) {
    const int t = w * 4 + tt;
    float4 v = *reinterpret_cast<float4*>(&C[t * CS + lane * 4]);
    float s = v.x + v.y + v.z + v.w;
#pragma unroll
    for (int o = 32; o; o >>= 1) s += __shfl_xor(s, o);
    const float m = s * (1.f / 256.f);
    const float d0 = v.x - m, d1 = v.y - m, d2 = v.z - m, d3 = v.w - m;
    float s2 = d0 * d0 + d1 * d1 + d2 * d2 + d3 * d3;
#pragma unroll
    for (int o = 32; o; o >>= 1) s2 += __shfl_xor(s2, o);
    const float rs = rsqrtf(s2 * (1.f / 256.f) + 1e-5f);
    const float4 gg = *reinterpret_cast<const float4*>(&g[lane * 4]);
    const float4 bb = *reinterpret_cast<const float4*>(&be[lane * 4]);
    float4 o4;
    o4.x = d0 * rs * gg.x + bb.x; o4.y = d1 * rs * gg.y + bb.y;
    o4.z = d2 * rs * gg.z + bb.z; o4.w = d3 * rs * gg.w + bb.w;
    ushort4 ob; ob.x = f2b(o4.x); ob.y = f2b(o4.y); ob.z = f2b(o4.z); ob.w = f2b(o4.w);
    *reinterpret_cast<ushort4*>(&A[t * AS + lane * 4]) = ob;
  }
}

// ------------- k_vh: value role (bid even) + head role (bid odd) ------------

__global__ __launch_bounds__(512) void k_vh(
    const float* __restrict__ src, const float* __restrict__ tgt,
    const float* __restrict__ qp, const float* __restrict__ ref,
    const ushort* __restrict__ pw,
    const float* __restrict__ b_ds, const float* __restrict__ g_ds,
    const float* __restrict__ be_ds, const float* __restrict__ b_val,
    const float* __restrict__ b_off, const float* __restrict__ b_attn,
    unsigned* __restrict__ xy_g, ushort* __restrict__ aw_g,
    unsigned char* __restrict__ dout) {
  __shared__ __align__(16) ushort A[TT2 * AS];
  __shared__ __align__(16) float  C[TT2 * CS];
  const int tid = threadIdx.x, w = tid >> 6, lane = tid & 63;
  const int bid = blockIdx.x;
  const int tok0 = (bid >> 1) * TT2;

  if ((bid & 1) == 0) {
    // ================= value role =================
    load_to_A32<false>(src, nullptr, tok0, A, w, lane);
    __syncthreads();
    f32x4 acc[2][2];
    gemm_tile32<2>(A, pw + PW_DS, w * 2, lane, acc);
    acc_to_c32<2>(acc, C, b_ds, w * 2, lane, CS);
    __syncthreads();
    ln_c_to_a32(C, A, g_ds, be_ds, w, lane);
    __syncthreads();
    gemm_tile32<2>(A, pw + PW_VAL, w * 2, lane, acc);
    acc_to_c32<2>(acc, C, b_val, w * 2, lane, CS);
    __syncthreads();
#pragma unroll
    for (int tt = 0; tt < 4; ++tt) {
      const int t = w * 4 + tt, tok = tok0 + t;
      if (tok < NTOK) {
        const float4 v = *reinterpret_cast<const float4*>(&C[t * CS + lane * 4]);
        ushort4 b; b.x = f2b(v.x); b.y = f2b(v.y); b.z = f2b(v.z); b.w = f2b(v.w);
        *reinterpret_cast<ushort4*>(dout + (size_t)tok * 1024 + 512 + lane * 8) = b;
      }
    }
  } else {
    // ================= head role =================
    float* AW = (float*)A;                        // aliases q tile after GEMM
    load_to_A32<true>(tgt, qp, tok0, A, w, lane);
    __syncthreads();

    f32x4 acc[2][3];
    gemm_tile32<3>(A, pw + PW_OFA, w * 3, lane, acc);
    __syncthreads();   // all waves done reading A (q) -> AW alias safe
    {
      const int col = lane & 15, rb = (lane >> 4) * 4;
#pragma unroll
      for (int m = 0; m < 2; ++m)
#pragma unroll
        for (int j = 0; j < 3; ++j) {
          const int g = w * 3 + j;
          if (g < 16) {
            const int dim = g * 16 + col;
            const float bj = b_off[dim];
#pragma unroll
            for (int i = 0; i < 4; ++i)
              C[(m * 16 + rb + i) * CS + dim] = acc[m][j][i] + bj;
          } else {
            const int adim = (g - 16) * 16 + col;
            const float bj = b_attn[adim];
#pragma unroll
            for (int i = 0; i < 4; ++i)
              AW[(m * 16 + rb + i) * AWS + adim] = acc[m][j][i] + bj;
          }
        }
    }
    __syncthreads();

    // softmax over 16 per (token, head): 256 of 512 threads
    if (tid < TT2 * 8) {
      const int t = tid >> 3, h = tid & 7;
      float* a = &AW[t * AWS + h * 16];
      float m = a[0];
#pragma unroll
      for (int i = 1; i < 16; ++i) m = fmaxf(m, a[i]);
      float s = 0.f, e[16];
#pragma unroll
      for (int i = 0; i < 16; ++i) { e[i] = expf(a[i] - m); s += e[i]; }
      const float inv = 1.0f / s;
#pragma unroll
      for (int i = 0; i < 16; ++i) a[i] = e[i] * inv;
    }
    __syncthreads();

    // descriptors: thread -> (quarter = tid>>7, pt = tid&127); 8 tokens each
    {
      const int quarter = tid >> 7, pt = tid & 127;
      const int l = (pt >> 2) & 3;
      const int Wl = (l == 0) ? 92 : (l == 1) ? 46 : (l == 2) ? 23 : 12;
      const float fW = (float)Wl;
#pragma unroll
      for (int it = 0; it < 8; ++it) {
        const int tl = quarter * 8 + it;
        const int tok = tok0 + tl;
        const int tokc = (tok < NTOK) ? tok : (NTOK - 1);
        const float refx = ref[(size_t)tokc * 8 + l * 2 + 0];
        const float refy = ref[(size_t)tokc * 8 + l * 2 + 1];
        const float vmask = (tok < NTOK) ? 1.f : 0.f;
        const float2 oxy = *reinterpret_cast<const float2*>(&C[tl * CS + pt * 2]);
        const float aw = AW[tl * AWS + pt] * vmask;
        float x = fmaf(refx, fW, oxy.x) - 0.5f;
        float y = fmaf(refy, fW, oxy.y) - 0.5f;
        x = fminf(fmaxf(x, -1.f), 126.9f);
        y = fminf(fmaxf(y, -1.f), 126.9f);
        const unsigned ux = (unsigned)(int)rintf((x + 1.f) * 512.f);
        const unsigned uy = (unsigned)(int)rintf((y + 1.f) * 512.f);
        xy_g[(size_t)tok * 128 + pt] = ux | (uy << 16);
        aw_g[(size_t)tok * 128 + pt] = __half_as_ushort(__float2half_rn(aw));
      }
    }
  }
}

// ------------- kernel 3: gather — R9 serial chain, uint4 width (2 tok/wave) -
// Decode math kept BYTE-EQUIVALENT to R9 (the serial per-point chain paces
// the load stream; R5/R8/R10 proved slimming it thrashes L2). Change: each
// lane carries 8 elements (uint4) instead of 4 (uint2) -> decode redundancy
// 8x -> 4x, VALU/elem -30%, VALU-per-load-instr UP (pacing preserved).
// LDS descriptor stride 136/17 makes the 16-address broadcast conflict-free.

__global__ __launch_bounds__(256, 6) void k_gather(
    const unsigned* __restrict__ xy_g, const ushort* __restrict__ aw_g,
    unsigned char* __restrict__ dout) {
  __shared__ unsigned sxy[8 * 136];
  __shared__ ushort   saw[8 * 136];
  const int tid = threadIdx.x;

  // bijective XCD swizzle: gblk = 2814 = 8*351 + 6 (q=351, r=6; m204 variant)
  const int bid = blockIdx.x;
  const int xcd = bid & 7, pos = bid >> 3;
  const int swz = (xcd < 6) ? (xcd * 352 + pos) : (6 * 352 + (xcd - 6) * 351 + pos);
  const int tb0 = swz * 8;

  // stage 8 tokens' descriptors (conflict-free strided layout)
#pragma unroll
  for (int i = 0; i < 4; ++i) {
    const int idx = tid + i * 256;
    const int stl = idx >> 7, srem = idx & 127;
    const int so = stl * 136 + (srem >> 4) * 17 + (srem & 15);
    sxy[so] = xy_g[(size_t)tb0 * 128 + idx];
    saw[so] = aw_g[(size_t)tb0 * 128 + idx];
  }
  __syncthreads();

  const int tl = tid >> 5;                 // token within block (0..7)
  const int h = (tid >> 2) & 7, sl = tid & 3;
  const int tok = tb0 + tl;
  const int bb = (tok >= LQ) ? LQ : 0;
  const int dbase = tl * 136 + h * 17;     // descriptor base in LDS
  const int cb = 512 + h * 64 + sl * 16;   // value byte offset within slot
  const unsigned char* __restrict__ vb = dout;

  float o0 = 0.f, o1 = 0.f, o2 = 0.f, o3 = 0.f;
  float o4 = 0.f, o5 = 0.f, o6 = 0.f, o7 = 0.f;
#pragma unroll
  for (int l = 0; l < 4; ++l) {
    const int Wl  = (l == 0) ? 92 : (l == 1) ? 46 : (l == 2) ? 23 : 12;
    const int lsi = (l == 0) ? 0  : (l == 1) ? 8464 : (l == 2) ? 10580 : 11109;
    const int rbas = bb + lsi;
#pragma unroll
    for (int p = 0; p < 4; ++p) {
      const int pt = l * 4 + p;
      const unsigned uxy = sxy[dbase + pt];
      const float aw = __half2float(__ushort_as_half(saw[dbase + pt]));
      const float x = (float)(uxy & 0xffffu) * (1.f / 512.f) - 1.f;
      const float y = (float)(uxy >> 16)     * (1.f / 512.f) - 1.f;
      const float x0f = floorf(x), y0f = floorf(y);
      const int x0 = (int)x0f, y0 = (int)y0f;
      const float fx = x - x0f, fy = y - y0f;
      const float gx = 1.f - fx, gy = 1.f - fy;
      const float wx0 = ((x0 >= 0) & (x0 < Wl)) ? gx : 0.f;
      const float wx1 = (x0 < Wl - 1) ? fx : 0.f;
      const float wy0 = (((y0 >= 0) & (y0 < Wl)) ? gy : 0.f) * aw;
      const float wy1 = ((y0 < Wl - 1) ? fy : 0.f) * aw;
      const float w00 = wx0 * wy0, w10 = wx1 * wy0;
      const float w01 = wx0 * wy1, w11 = wx1 * wy1;
      const int base = rbas + y0 * Wl + x0;
      const int r00 = clampr(base),      r10 = clampr(base + 1);
      const int r01 = clampr(base + Wl), r11 = clampr(base + Wl + 1);
      const uint4 u00 = *(const uint4*)(vb + (size_t)r00 * 1024 + cb);
      const uint4 u10 = *(const uint4*)(vb + (size_t)r10 * 1024 + cb);
      const uint4 u01 = *(const uint4*)(vb + (size_t)r01 * 1024 + cb);
      const uint4 u11 = *(const uint4*)(vb + (size_t)r11 * 1024 + cb);
      o0 = fmaf(w00, blo(u00.x), o0); o1 = fmaf(w00, bhi(u00.x), o1);
      o2 = fmaf(w00, blo(u00.y), o2); o3 = fmaf(w00, bhi(u00.y), o3);
      o4 = fmaf(w00, blo(u00.z), o4); o5 = fmaf(w00, bhi(u00.z), o5);
      o6 = fmaf(w00, blo(u00.w), o6); o7 = fmaf(w00, bhi(u00.w), o7);
      o0 = fmaf(w10, blo(u10.x), o0); o1 = fmaf(w10, bhi(u10.x), o1);
      o2 = fmaf(w10, blo(u10.y), o2); o3 = fmaf(w10, bhi(u10.y), o3);
      o4 = fmaf(w10, blo(u10.z), o4); o5 = fmaf(w10, bhi(u10.z), o5);
      o6 = fmaf(w10, blo(u10.w), o6); o7 = fmaf(w10, bhi(u10.w), o7);
      o0 = fmaf(w01, blo(u01.x), o0); o1 = fmaf(w01, bhi(u01.x), o1);
      o2 = fmaf(w01, blo(u01.y), o2); o3 = fmaf(w01, bhi(u01.y), o3);
      o4 = fmaf(w01, blo(u01.z), o4); o5 = fmaf(w01, bhi(u01.z), o5);
      o6 = fmaf(w01, blo(u01.w), o6); o7 = fmaf(w01, bhi(u01.w), o7);
      o0 = fmaf(w11, blo(u11.x), o0); o1 = fmaf(w11, bhi(u11.x), o1);
      o2 = fmaf(w11, blo(u11.y), o2); o3 = fmaf(w11, bhi(u11.y), o3);
      o4 = fmaf(w11, blo(u11.z), o4); o5 = fmaf(w11, bhi(u11.z), o5);
      o6 = fmaf(w11, blo(u11.w), o6); o7 = fmaf(w11, bhi(u11.w), o7);
    }
  }
  if (tok < NTOK) {
    uint4 st;
    st.x = (unsigned)f2b(o0) | ((unsigned)f2b(o1) << 16);
    st.y = (unsigned)f2b(o2) | ((unsigned)f2b(o3) << 16);
    st.z = (unsigned)f2b(o4) | ((unsigned)f2b(o5) << 16);
    st.w = (unsigned)f2b(o6) | ((unsigned)f2b(o7) << 16);
    *(uint4*)(dout + (size_t)tok * 1024 + h * 64 + sl * 16) = st;
  }
}

// ------------- kernel 4: tail = ATT@w_oc (+tgt, LN1) @w1 (GELU+res, LN2) ----

__global__ __launch_bounds__(512) void k_tail(
    const float* __restrict__ tgt, const ushort* __restrict__ pw,
    const float* __restrict__ b_oc,
    const float* __restrict__ g1, const float* __restrict__ be1,
    const float* __restrict__ b1,
    const float* __restrict__ g2, const float* __restrict__ be2,
    unsigned char* __restrict__ dout) {
  __shared__ __align__(16) ushort A[TT2 * AS];
  __shared__ __align__(16) float  C[TT2 * CS];
  const int tid = threadIdx.x, w = tid >> 6, lane = tid & 63;
  const int tok0 = blockIdx.x * TT2;

  // load ATT (bf16) rows from our own d_out slots: 4 rows per wave
#pragma unroll
  for (int tt = 0; tt < 4; ++tt) {
    const int t = w * 4 + tt, tok = tok0 + t;
    ushort4 b = make_ushort4(0, 0, 0, 0);
    if (tok < NTOK)
      b = *reinterpret_cast<const ushort4*>(dout + (size_t)tok * 1024 + lane * 8);
    *reinterpret_cast<ushort4*>(&A[t * AS + lane * 4]) = b;
  }
  __syncthreads();

  f32x4 acc[2][2];
  // t2 = ATT @ w_oc + b_oc   (fused w_out@w_cs)
  gemm_tile32<2>(A, pw + PW_OC, w * 2, lane, acc);
  acc_to_c32<2>(acc, C, b_oc, w * 2, lane, CS);
  __syncthreads();

  // LN1 over (t2 + tgt): coalesced tgt read; writeback t to C, bf16 to A
#pragma unroll
  for (int tt = 0; tt < 4; ++tt) {
    const int t = w * 4 + tt, tok = tok0 + t;
    float4 v = *reinterpret_cast<float4*>(&C[t * CS + lane * 4]);
    if (tok < NTOK) {
      const float4 r = *reinterpret_cast<const float4*>(&tgt[(size_t)tok * DM + lane * 4]);
      v.x += r.x; v.y += r.y; v.z += r.z; v.w += r.w;
    }
    float s = v.x + v.y + v.z + v.w;
#pragma unroll
    for (int o = 32; o; o >>= 1) s += __shfl_xor(s, o);
    const float m = s * (1.f / 256.f);
    const float d0 = v.x - m, d1 = v.y - m, d2 = v.z - m, d3 = v.w - m;
    float s2 = d0 * d0 + d1 * d1 + d2 * d2 + d3 * d3;
#pragma unroll
    for (int o = 32; o; o >>= 1) s2 += __shfl_xor(s2, o);
    const float rs = rsqrtf(s2 * (1.f / 256.f) + 1e-5f);
    const float4 gg = *reinterpret_cast<const float4*>(&g1[lane * 4]);
    const float4 bb = *reinterpret_cast<const float4*>(&be1[lane * 4]);
    float4 o4;
    o4.x = d0 * rs * gg.x + bb.x; o4.y = d1 * rs * gg.y + bb.y;
    o4.z = d2 * rs * gg.z + bb.z; o4.w = d3 * rs * gg.w + bb.w;
    ushort4 ob; ob.x = f2b(o4.x); ob.y = f2b(o4.y); ob.z = f2b(o4.z); ob.w = f2b(o4.w);
    *reinterpret_cast<ushort4*>(&A[t * AS + lane * 4]) = ob;
    *reinterpret_cast<float4*>(&C[t * CS + lane * 4]) = o4;
  }
  __syncthreads();

  // u = gelu(t @ w1 + b1); y = t + u (in-place on C)
  gemm_tile32<2>(A, pw + PW_W1, w * 2, lane, acc);
  {
    const int col = lane & 15, rb = (lane >> 4) * 4;
#pragma unroll
    for (int m = 0; m < 2; ++m)
#pragma unroll
      for (int nt = 0; nt < 2; ++nt) {
        const int dim = (w * 2 + nt) * 16 + col;
        const float bj = b1[dim];
#pragma unroll
        for (int i = 0; i < 4; ++i) {
          const float x = acc[m][nt][i] + bj;
          const float gel = 0.5f * x * (1.0f + erff(x * 0.70710678118654752f));
          const int ci = (m * 16 + rb + i) * CS + dim;
          C[ci] = C[ci] + gel;
        }
      }
  }
  __syncthreads();

  // LN2 -> out (fp32 full slot overwrite): 4 rows per wave
  float* outp = (float*)dout;
#pragma unroll
  for (int tt = 0; tt < 4; ++tt) {
    const int t = w * 4 + tt, tok = tok0 + t;
    float4 v = *reinterpret_cast<float4*>(&C[t * CS + lane * 4]);
    float s = v.x + v.y + v.z + v.w;
#pragma unroll
    for (int o = 32; o; o >>= 1) s += __shfl_xor(s, o);
    const float m = s * (1.f / 256.f);
    const float d0 = v.x - m, d1 = v.y - m, d2 = v.z - m, d3 = v.w - m;
    float s2 = d0 * d0 + d1 * d1 + d2 * d2 + d3 * d3;
#pragma unroll
    for (int o = 32; o; o >>= 1) s2 += __shfl_xor(s2, o);
    const float rs = rsqrtf(s2 * (1.f / 256.f) + 1e-5f);
    if (tok < NTOK) {
      const float4 gg = *reinterpret_cast<const float4*>(&g2[lane * 4]);
      const float4 bb = *reinterpret_cast<const float4*>(&be2[lane * 4]);
      float4 o4;
      o4.x = d0 * rs * gg.x + bb.x; o4.y = d1 * rs * gg.y + bb.y;
      o4.z = d2 * rs * gg.z + bb.z; o4.w = d3 * rs * gg.w + bb.w;
      *reinterpret_cast<float4*>(&outp[(size_t)tok * DM + lane * 4]) = o4;
    }
  }
}

// ---------------- launch ----------------

extern "C" void kernel_launch(void* const* d_in, const int* in_sizes, int n_in,
                              void* d_out, int out_size, void* d_ws, size_t ws_size,
                              hipStream_t stream) {
  const float* tgt    = (const float*)d_in[0];
  const float* qp     = (const float*)d_in[1];
  const float* ref    = (const float*)d_in[2];
  const float* src    = (const float*)d_in[3];
  const float* w_ds   = (const float*)d_in[6];
  const float* b_ds   = (const float*)d_in[7];
  const float* g_ds   = (const float*)d_in[8];
  const float* be_ds  = (const float*)d_in[9];
  const float* w_off  = (const float*)d_in[10];
  const float* b_off  = (const float*)d_in[11];
  const float* w_attn = (const float*)d_in[12];
  const float* b_attn = (const float*)d_in[13];
  const float* w_val  = (const float*)d_in[14];
  const float* b_val  = (const float*)d_in[15];
  const float* w_out  = (const float*)d_in[16];
  const float* b_out  = (const float*)d_in[17];
  const float* w_cs   = (const float*)d_in[18];
  const float* b_cs   = (const float*)d_in[19];
  const float* g1     = (const float*)d_in[20];
  const float* be1    = (const float*)d_in[21];
  const float* w1     = (const float*)d_in[22];
  const float* b1     = (const float*)d_in[23];
  const float* g2     = (const float*)d_in[24];
  const float* be2    = (const float*)d_in[25];

  ushort*   pw   = (ushort*)d_ws;
  float*    b_oc = (float*)((char*)d_ws + B_OC_OFF);
  unsigned* xy_g = (unsigned*)((char*)d_ws + XY_WS_OFF);
  ushort*   aw_g = (ushort*)((char*)d_ws + AW_WS_OFF);
  unsigned char* dout = (unsigned char*)d_out;

  const int gblk = (NTOK + 7) / 8;             // 2814
  hipLaunchKernelGGL(k_prep, dim3(209), dim3(256), 0, stream,
                     w_ds, w_val, w_off, w1, w_attn, w_out, w_cs, b_out, b_cs,
                     pw, b_oc);
  hipLaunchKernelGGL(k_vh, dim3(2 * NBLK32), dim3(512), 0, stream,
                     src, tgt, qp, ref, pw, b_ds, g_ds, be_ds, b_val,
                     b_off, b_attn, xy_g, aw_g, dout);
  hipLaunchKernelGGL(k_gather, dim3(gblk), dim3(256), 0, stream,
                     xy_g, aw_g, dout);
  hipLaunchKernelGGL(k_tail, dim3(NBLK32), dim3(512), 0, stream,
                     tgt, pw, b_oc, g1, be1, b1, g2, be2, dout);
}

// Round 14
// 129.594 us; speedup vs baseline: 6.4296x; 6.4296x over previous
//
#include <hip/hip_runtime.h>
#include <hip/hip_fp16.h>
#include <math.h>

// Problem constants (fixed by setup_inputs)
#define DM    256
#define LQ    11253
#define NTOK  (2*LQ)        // 22506
#define TT2   32            // tokens per block (GEMM kernels)
#define NBLK32 704          // ceil(NTOK/32)
#define AS    264           // ushorts per A (bf16) LDS row: 256 + 8 pad
#define CS    260           // floats per C (fp32) LDS row: 256 + 4 pad
#define AWS   132           // floats per AW row: 128 + 4 pad

typedef __attribute__((ext_vector_type(8))) short bf16x8;
typedef __attribute__((ext_vector_type(4))) float f32x4;

// packed-weight offsets (ushort units)
#define PW_DS  0
#define PW_VAL 65536
#define PW_OFA 131072      // w_off (nt 0..15) ++ w_attn (nt 16..23), 98304 ushorts
#define PW_W1  229376
#define PW_OC  294912      // w_out @ w_cs fused
// ws layout (bytes): pw [0,~721K) | b_oc [860160,861184) | xy [1MiB,12MiB) | aw [12MiB,~17.8MiB)
#define B_OC_OFF  860160u
#define XY_WS_OFF (1u<<20)
#define AW_WS_OFF (12u<<20)
// d_out layout: per token a 1024B slot: ATT bf16 [0,512) | value bf16 [512,1024)

// ---------------- small helpers ----------------

__device__ __forceinline__ ushort f2b(float x) {   // fp32 -> bf16 (RNE)
  union { float f; unsigned u; } c; c.f = x;
  unsigned u = c.u + 0x7fffu + ((c.u >> 16) & 1u);
  return (ushort)(u >> 16);
}
__device__ __forceinline__ float blo(unsigned u) {
  union { unsigned u; float f; } c; c.u = u << 16; return c.f;
}
__device__ __forceinline__ float bhi(unsigned u) {
  union { unsigned u; float f; } c; c.u = u & 0xffff0000u; return c.f;
}
__device__ __forceinline__ int clampr(int v) { return min(max(v, 0), NTOK - 1); }

// ------------- k_prep: weight pack (144 blk) + w_oc matmul (64) + b_oc (1) --

__global__ __launch_bounds__(256) void k_prep(
    const float* __restrict__ w_ds, const float* __restrict__ w_val,
    const float* __restrict__ w_off, const float* __restrict__ w1,
    const float* __restrict__ wa,
    const float* __restrict__ w_out, const float* __restrict__ w_cs,
    const float* __restrict__ b_out, const float* __restrict__ b_cs,
    ushort* __restrict__ pw, float* __restrict__ b_oc) {
  __shared__ float rows[4][256];
  const int bid = blockIdx.x, j = threadIdx.x;

  if (bid < 144) {
    // ---- pack role: fp32 [K][N] -> bf16 MFMA B-fragments ----
    const int gid = bid * 256 + j;
    const float* W; int N; size_t obase; int local; int ntAdd;
    if (gid < 4 * 8192) {
      const int wi = gid >> 13; local = gid & 8191; N = 256; ntAdd = 0;
      obase = (wi == 0) ? PW_DS : (wi == 1) ? PW_VAL : (wi == 2) ? PW_OFA : PW_W1;
      W = (wi == 0) ? w_ds : (wi == 1) ? w_val : (wi == 2) ? w_off : w1;
    } else {
      local = gid - 32768; N = 128; obase = PW_OFA; W = wa; ntAdd = 16;
    }
    const int l = local & 63, f = local >> 6;
    const int kt = f & 7, nt = f >> 3;
    const int k0 = kt * 32 + (l >> 4) * 8, col = nt * 16 + (l & 15);
    ushort v[8];
#pragma unroll
    for (int e = 0; e < 8; ++e) v[e] = f2b(W[(size_t)(k0 + e) * N + col]);
    const size_t fout = (size_t)(((nt + ntAdd) * 8 + kt) * 64 + l);
    *reinterpret_cast<uint4*>(&pw[obase + fout * 8]) =
        *reinterpret_cast<const uint4*>(v);
  } else if (bid < 208) {
    // ---- oc matmul role: w_oc = w_out @ w_cs, 4 K-rows per block ----
    const int k0 = (bid - 144) * 4;
#pragma unroll
    for (int rr = 0; rr < 4; ++rr) rows[rr][j] = w_out[(size_t)(k0 + rr) * 256 + j];
    __syncthreads();
    float s[4];
#pragma unroll
    for (int rr = 0; rr < 4; ++rr) s[rr] = 0.f;
    for (int m = 0; m < 256; ++m) {
      const float c = w_cs[(size_t)m * 256 + j];
#pragma unroll
      for (int rr = 0; rr < 4; ++rr) s[rr] = fmaf(rows[rr][m], c, s[rr]);
    }
    const int nt = j >> 4;
#pragma unroll
    for (int rr = 0; rr < 4; ++rr) {
      const int k = k0 + rr;
      const int kt = k >> 5, ln = ((k >> 3) & 3) * 16 + (j & 15), e = k & 7;
      pw[PW_OC + ((size_t)((nt * 8 + kt) * 64 + ln)) * 8 + e] = f2b(s[rr]);
    }
  } else {
    // ---- b_oc role ----
    float s = b_cs[j];
    for (int m = 0; m < 256; ++m) s = fmaf(b_out[m], w_cs[(size_t)m * 256 + j], s);
    b_oc[j] = s;
  }
}

// -------- GEMM tile helpers: 512 threads, 8 waves, 32 tokens, B reused x2 ---

template<int NTW>
__device__ __forceinline__ void gemm_tile32(const ushort* __restrict__ A,
                                            const ushort* __restrict__ Bp,
                                            int ntBase, int lane,
                                            f32x4 (&acc)[2][NTW]) {
  const int r = lane & 15, hk = lane >> 4;
  const ushort* arow0 = A + r * AS + hk * 8;
  const ushort* arow1 = A + (r + 16) * AS + hk * 8;
#pragma unroll
  for (int m = 0; m < 2; ++m)
#pragma unroll
    for (int nt = 0; nt < NTW; ++nt) acc[m][nt] = (f32x4){0.f, 0.f, 0.f, 0.f};
#pragma unroll
  for (int kt = 0; kt < 8; ++kt) {
    const bf16x8 a0 = *(const bf16x8*)(arow0 + kt * 32);
    const bf16x8 a1 = *(const bf16x8*)(arow1 + kt * 32);
#pragma unroll
    for (int nt = 0; nt < NTW; ++nt) {
      const bf16x8 b = *(const bf16x8*)(Bp + ((size_t)((ntBase + nt) * 8 + kt) * 64 + lane) * 8);
      acc[0][nt] = __builtin_amdgcn_mfma_f32_16x16x32_bf16(a0, b, acc[0][nt], 0, 0, 0);
      acc[1][nt] = __builtin_amdgcn_mfma_f32_16x16x32_bf16(a1, b, acc[1][nt], 0, 0, 0);
    }
  }
}

template<int NTW>
__device__ __forceinline__ void acc_to_c32(const f32x4 (&acc)[2][NTW], float* C,
                                           const float* __restrict__ bias,
                                           int ntBase, int lane, int rowStride) {
  const int col = lane & 15, rb = (lane >> 4) * 4;
#pragma unroll
  for (int m = 0; m < 2; ++m)
#pragma unroll
    for (int nt = 0; nt < NTW; ++nt) {
      const int dim = (ntBase + nt) * 16 + col;
      const float bj = bias[dim];
#pragma unroll
      for (int i = 0; i < 4; ++i)
        C[(m * 16 + rb + i) * rowStride + dim] = acc[m][nt][i] + bj;
    }
}

// 8 waves x 4 rows each = 32 rows
template<bool ADD>
__device__ __forceinline__ void load_to_A32(const float* __restrict__ X,
                                            const float* __restrict__ Y,
                                            int tok0, ushort* A, int w, int lane) {
#pragma unroll
  for (int tt = 0; tt < 4; ++tt) {
    const int t = w * 4 + tt, tok = tok0 + t;
    float4 v = make_float4(0.f, 0.f, 0.f, 0.f);
    if (tok < NTOK) {
      v = *reinterpret_cast<const float4*>(&X[(size_t)tok * DM + lane * 4]);
      if (ADD) {
        const float4 y = *reinterpret_cast<const float4*>(&Y[(size_t)tok * DM + lane * 4]);
        v.x += y.x; v.y += y.y; v.z += y.z; v.w += y.w;
      }
    }
    ushort4 b; b.x = f2b(v.x); b.y = f2b(v.y); b.z = f2b(v.z); b.w = f2b(v.w);
    *reinterpret_cast<ushort4*>(&A[t * AS + lane * 4]) = b;
  }
}

// LayerNorm rows of C -> bf16 into A; 8 waves x 4 rows each
__device__ __forceinline__ void ln_c_to_a32(float* C, ushort* A,
                                            const float* __restrict__ g,
                                            const float* __restrict__ be,
                                            int w, int lane) {
#pragma unroll
  for (int tt = 0; tt < 4; ++tt) {
    const int t = w * 4 + tt;
    float4 v = *reinterpret_cast<float4*>(&C[t * CS + lane * 4]);
    float s = v.x + v.y + v.z + v.w;
#pragma unroll
    for (int o = 32; o; o >>= 1) s += __shfl_xor(s, o);
    const float m = s * (1.f / 256.f);
    const float d0 = v.x - m, d1 = v.y - m, d2 = v.z - m, d3 = v.w - m;
    float s2 = d0 * d0 + d1 * d1 + d2 * d2 + d3 * d3;
#pragma unroll
    for (int o = 32; o; o >>= 1) s2 += __shfl_xor(s2, o);
    const float rs = rsqrtf(s2 * (1.f / 256.f) + 1e-5f);
    const float4 gg = *reinterpret_cast<const float4*>(&g[lane * 4]);
    const float4 bb = *reinterpret_cast<const float4*>(&be[lane * 4]);
    float4 o4;
    o4.x = d0 * rs * gg.x + bb.x; o4.y = d1 * rs * gg.y + bb.y;
    o4.z = d2 * rs * gg.z + bb.z; o4.w = d3 * rs * gg.w + bb.w;
    ushort4 ob; ob.x = f2b(o4.x); ob.y = f2b(o4.y); ob.z = f2b(o4.z); ob.w = f2b(o4.w);
    *reinterpret_cast<ushort4*>(&A[t * AS + lane * 4]) = ob;
  }
}

// ------------- k_vh: value role (bid even) + head role (bid odd) ------------

__global__ __launch_bounds__(512) void k_vh(
    const float* __restrict__ src, const float* __restrict__ tgt,
    const float* __restrict__ qp, const float* __restrict__ ref,
    const ushort* __restrict__ pw,
    const float* __restrict__ b_ds, const float* __restrict__ g_ds,
    const float* __restrict__ be_ds, const float* __restrict__ b_val,
    const float* __restrict__ b_off, const float* __restrict__ b_attn,
    unsigned* __restrict__ xy_g, ushort* __restrict__ aw_g,
    unsigned char* __restrict__ dout) {
  __shared__ __align__(16) ushort A[TT2 * AS];
  __shared__ __align__(16) float  C[TT2 * CS];
  const int tid = threadIdx.x, w = tid >> 6, lane = tid & 63;
  const int bid = blockIdx.x;
  const int tok0 = (bid >> 1) * TT2;

  if ((bid & 1) == 0) {
    // ================= value role =================
    load_to_A32<false>(src, nullptr, tok0, A, w, lane);
    __syncthreads();
    f32x4 acc[2][2];
    gemm_tile32<2>(A, pw + PW_DS, w * 2, lane, acc);
    acc_to_c32<2>(acc, C, b_ds, w * 2, lane, CS);
    __syncthreads();
    ln_c_to_a32(C, A, g_ds, be_ds, w, lane);
    __syncthreads();
    gemm_tile32<2>(A, pw + PW_VAL, w * 2, lane, acc);
    acc_to_c32<2>(acc, C, b_val, w * 2, lane, CS);
    __syncthreads();
#pragma unroll
    for (int tt = 0; tt < 4; ++tt) {
      const int t = w * 4 + tt, tok = tok0 + t;
      if (tok < NTOK) {
        const float4 v = *reinterpret_cast<const float4*>(&C[t * CS + lane * 4]);
        ushort4 b; b.x = f2b(v.x); b.y = f2b(v.y); b.z = f2b(v.z); b.w = f2b(v.w);
        *reinterpret_cast<ushort4*>(dout + (size_t)tok * 1024 + 512 + lane * 8) = b;
      }
    }
  } else {
    // ================= head role =================
    float* AW = (float*)A;                        // aliases q tile after GEMM
    load_to_A32<true>(tgt, qp, tok0, A, w, lane);
    __syncthreads();

    f32x4 acc[2][3];
    gemm_tile32<3>(A, pw + PW_OFA, w * 3, lane, acc);
    __syncthreads();   // all waves done reading A (q) -> AW alias safe
    {
      const int col = lane & 15, rb = (lane >> 4) * 4;
#pragma unroll
      for (int m = 0; m < 2; ++m)
#pragma unroll
        for (int j = 0; j < 3; ++j) {
          const int g = w * 3 + j;
          if (g < 16) {
            const int dim = g * 16 + col;
            const float bj = b_off[dim];
#pragma unroll
            for (int i = 0; i < 4; ++i)
              C[(m * 16 + rb + i) * CS + dim] = acc[m][j][i] + bj;
          } else {
            const int adim = (g - 16) * 16 + col;
            const float bj = b_attn[adim];
#pragma unroll
            for (int i = 0; i < 4; ++i)
              AW[(m * 16 + rb + i) * AWS + adim] = acc[m][j][i] + bj;
          }
        }
    }
    __syncthreads();

    // softmax over 16 per (token, head): 256 of 512 threads
    if (tid < TT2 * 8) {
      const int t = tid >> 3, h = tid & 7;
      float* a = &AW[t * AWS + h * 16];
      float m = a[0];
#pragma unroll
      for (int i = 1; i < 16; ++i) m = fmaxf(m, a[i]);
      float s = 0.f, e[16];
#pragma unroll
      for (int i = 0; i < 16; ++i) { e[i] = expf(a[i] - m); s += e[i]; }
      const float inv = 1.0f / s;
#pragma unroll
      for (int i = 0; i < 16; ++i) a[i] = e[i] * inv;
    }
    __syncthreads();

    // descriptors: thread -> (quarter = tid>>7, pt = tid&127); 8 tokens each
    {
      const int quarter = tid >> 7, pt = tid & 127;
      const int l = (pt >> 2) & 3;
      const int Wl = (l == 0) ? 92 : (l == 1) ? 46 : (l == 2) ? 23 : 12;
      const float fW = (float)Wl;
#pragma unroll
      for (int it = 0; it < 8; ++it) {
        const int tl = quarter * 8 + it;
        const int tok = tok0 + tl;
        const int tokc = (tok < NTOK) ? tok : (NTOK - 1);
        const float refx = ref[(size_t)tokc * 8 + l * 2 + 0];
        const float refy = ref[(size_t)tokc * 8 + l * 2 + 1];
        const float vmask = (tok < NTOK) ? 1.f : 0.f;
        const float2 oxy = *reinterpret_cast<const float2*>(&C[tl * CS + pt * 2]);
        const float aw = AW[tl * AWS + pt] * vmask;
        float x = fmaf(refx, fW, oxy.x) - 0.5f;
        float y = fmaf(refy, fW, oxy.y) - 0.5f;
        x = fminf(fmaxf(x, -1.f), 126.9f);
        y = fminf(fmaxf(y, -1.f), 126.9f);
        const unsigned ux = (unsigned)(int)rintf((x + 1.f) * 512.f);
        const unsigned uy = (unsigned)(int)rintf((y + 1.f) * 512.f);
        xy_g[(size_t)tok * 128 + pt] = ux | (uy << 16);
        aw_g[(size_t)tok * 128 + pt] = __half_as_ushort(__float2half_rn(aw));
      }
    }
  }
}

// ------------- kernel 3: gather — R9-exact FROZEN (proven 55.5 µs optimum) --
// Per-lane inline descriptor math intentionally kept: the VALU chain paces the
// load stream so the per-(token,level) 2x2 pixel clusters stay L2-resident.
// FOUR experiments (R5, R8, R10, R13) proved ANY perturbation of this issue
// structure (slim math, wider payloads, fewer waves) thrashes L2 (FETCH
// 55MB -> 97MB-1.2GB) and regresses 1.2-13x. Do not touch this kernel.

__global__ __launch_bounds__(256, 6) void k_gather(
    const unsigned* __restrict__ xy_g, const ushort* __restrict__ aw_g,
    unsigned char* __restrict__ dout) {
  __shared__ unsigned sxy[4 * 128];
  __shared__ ushort   saw[4 * 128];
  const int tid = threadIdx.x;

  // bijective XCD swizzle: gblk = 5627 = 8*703 + 3  (q=703, r=3; m204 variant)
  const int bid = blockIdx.x;
  const int xcd = bid & 7, pos = bid >> 3;
  const int swz = (xcd < 3) ? (xcd * 704 + pos) : (3 * 704 + (xcd - 3) * 703 + pos);
  const int tb0 = swz * 4;

  sxy[tid]       = xy_g[(size_t)tb0 * 128 + tid];
  sxy[tid + 256] = xy_g[(size_t)tb0 * 128 + tid + 256];
  saw[tid]       = aw_g[(size_t)tb0 * 128 + tid];
  saw[tid + 256] = aw_g[(size_t)tb0 * 128 + tid + 256];
  __syncthreads();

  const int tl = tid >> 6, h = (tid >> 3) & 7, sl = tid & 7;
  const int tok = tb0 + tl;
  const int bb = (tok >= LQ) ? LQ : 0;
  const int col8 = h * 16 + sl * 2;
  const unsigned char* __restrict__ vb = dout;

  float o0 = 0.f, o1 = 0.f, o2 = 0.f, o3 = 0.f;
#pragma unroll
  for (int l = 0; l < 4; ++l) {
    const int Wl  = (l == 0) ? 92 : (l == 1) ? 46 : (l == 2) ? 23 : 12;
    const int lsi = (l == 0) ? 0  : (l == 1) ? 8464 : (l == 2) ? 10580 : 11109;
    const int rbas = bb + lsi;
#pragma unroll
    for (int p = 0; p < 4; ++p) {
      const int pt = l * 4 + p;
      const unsigned uxy = sxy[tl * 128 + h * 16 + pt];
      const float aw = __half2float(__ushort_as_half(saw[tl * 128 + h * 16 + pt]));
      const float x = (float)(uxy & 0xffffu) * (1.f / 512.f) - 1.f;
      const float y = (float)(uxy >> 16)     * (1.f / 512.f) - 1.f;
      const float x0f = floorf(x), y0f = floorf(y);
      const int x0 = (int)x0f, y0 = (int)y0f;
      const float fx = x - x0f, fy = y - y0f;
      const float gx = 1.f - fx, gy = 1.f - fy;
      const float wx0 = ((x0 >= 0) & (x0 < Wl)) ? gx : 0.f;
      const float wx1 = (x0 < Wl - 1) ? fx : 0.f;
      const float wy0 = (((y0 >= 0) & (y0 < Wl)) ? gy : 0.f) * aw;
      const float wy1 = ((y0 < Wl - 1) ? fy : 0.f) * aw;
      const float w00 = wx0 * wy0, w10 = wx1 * wy0;
      const float w01 = wx0 * wy1, w11 = wx1 * wy1;
      const int base = rbas + y0 * Wl + x0;
      const int r00 = clampr(base),      r10 = clampr(base + 1);
      const int r01 = clampr(base + Wl), r11 = clampr(base + Wl + 1);
      const uint2 u00 = *(const uint2*)(vb + (size_t)r00 * 1024 + 512 + col8 * 4);
      const uint2 u10 = *(const uint2*)(vb + (size_t)r10 * 1024 + 512 + col8 * 4);
      const uint2 u01 = *(const uint2*)(vb + (size_t)r01 * 1024 + 512 + col8 * 4);
      const uint2 u11 = *(const uint2*)(vb + (size_t)r11 * 1024 + 512 + col8 * 4);
      o0 = fmaf(w00, blo(u00.x), o0); o1 = fmaf(w00, bhi(u00.x), o1);
      o2 = fmaf(w00, blo(u00.y), o2); o3 = fmaf(w00, bhi(u00.y), o3);
      o0 = fmaf(w10, blo(u10.x), o0); o1 = fmaf(w10, bhi(u10.x), o1);
      o2 = fmaf(w10, blo(u10.y), o2); o3 = fmaf(w10, bhi(u10.y), o3);
      o0 = fmaf(w01, blo(u01.x), o0); o1 = fmaf(w01, bhi(u01.x), o1);
      o2 = fmaf(w01, blo(u01.y), o2); o3 = fmaf(w01, bhi(u01.y), o3);
      o0 = fmaf(w11, blo(u11.x), o0); o1 = fmaf(w11, bhi(u11.x), o1);
      o2 = fmaf(w11, blo(u11.y), o2); o3 = fmaf(w11, bhi(u11.y), o3);
    }
  }
  if (tok < NTOK) {
    const unsigned lo = (unsigned)f2b(o0) | ((unsigned)f2b(o1) << 16);
    const unsigned hi = (unsigned)f2b(o2) | ((unsigned)f2b(o3) << 16);
    uint2 st; st.x = lo; st.y = hi;
    *(uint2*)(dout + (size_t)tok * 1024 + col8 * 4) = st;
  }
}

// ------------- kernel 4: tail = ATT@w_oc (+tgt, LN1) @w1 (GELU+res, LN2) ----

__global__ __launch_bounds__(512) void k_tail(
    const float* __restrict__ tgt, const ushort* __restrict__ pw,
    const float* __restrict__ b_oc,
    const float* __restrict__ g1, const float* __restrict__ be1,
    const float* __restrict__ b1,
    const float* __restrict__ g2, const float* __restrict__ be2,
    unsigned char* __restrict__ dout) {
  __shared__ __align__(16) ushort A[TT2 * AS];
  __shared__ __align__(16) float  C[TT2 * CS];
  const int tid = threadIdx.x, w = tid >> 6, lane = tid & 63;
  const int tok0 = blockIdx.x * TT2;

  // load ATT (bf16) rows from our own d_out slots: 4 rows per wave
#pragma unroll
  for (int tt = 0; tt < 4; ++tt) {
    const int t = w * 4 + tt, tok = tok0 + t;
    ushort4 b = make_ushort4(0, 0, 0, 0);
    if (tok < NTOK)
      b = *reinterpret_cast<const ushort4*>(dout + (size_t)tok * 1024 + lane * 8);
    *reinterpret_cast<ushort4*>(&A[t * AS + lane * 4]) = b;
  }
  __syncthreads();

  f32x4 acc[2][2];
  // t2 = ATT @ w_oc + b_oc   (fused w_out@w_cs)
  gemm_tile32<2>(A, pw + PW_OC, w * 2, lane, acc);
  acc_to_c32<2>(acc, C, b_oc, w * 2, lane, CS);
  __syncthreads();

  // LN1 over (t2 + tgt): coalesced tgt read; writeback t to C, bf16 to A
#pragma unroll
  for (int tt = 0; tt < 4; ++tt) {
    const int t = w * 4 + tt, tok = tok0 + t;
    float4 v = *reinterpret_cast<float4*>(&C[t * CS + lane * 4]);
    if (tok < NTOK) {
      const float4 r = *reinterpret_cast<const float4*>(&tgt[(size_t)tok * DM + lane * 4]);
      v.x += r.x; v.y += r.y; v.z += r.z; v.w += r.w;
    }
    float s = v.x + v.y + v.z + v.w;
#pragma unroll
    for (int o = 32; o; o >>= 1) s += __shfl_xor(s, o);
    const float m = s * (1.f / 256.f);
    const float d0 = v.x - m, d1 = v.y - m, d2 = v.z - m, d3 = v.w - m;
    float s2 = d0 * d0 + d1 * d1 + d2 * d2 + d3 * d3;
#pragma unroll
    for (int o = 32; o; o >>= 1) s2 += __shfl_xor(s2, o);
    const float rs = rsqrtf(s2 * (1.f / 256.f) + 1e-5f);
    const float4 gg = *reinterpret_cast<const float4*>(&g1[lane * 4]);
    const float4 bb = *reinterpret_cast<const float4*>(&be1[lane * 4]);
    float4 o4;
    o4.x = d0 * rs * gg.x + bb.x; o4.y = d1 * rs * gg.y + bb.y;
    o4.z = d2 * rs * gg.z + bb.z; o4.w = d3 * rs * gg.w + bb.w;
    ushort4 ob; ob.x = f2b(o4.x); ob.y = f2b(o4.y); ob.z = f2b(o4.z); ob.w = f2b(o4.w);
    *reinterpret_cast<ushort4*>(&A[t * AS + lane * 4]) = ob;
    *reinterpret_cast<float4*>(&C[t * CS + lane * 4]) = o4;
  }
  __syncthreads();

  // u = gelu(t @ w1 + b1); y = t + u (in-place on C)
  gemm_tile32<2>(A, pw + PW_W1, w * 2, lane, acc);
  {
    const int col = lane & 15, rb = (lane >> 4) * 4;
#pragma unroll
    for (int m = 0; m < 2; ++m)
#pragma unroll
      for (int nt = 0; nt < 2; ++nt) {
        const int dim = (w * 2 + nt) * 16 + col;
        const float bj = b1[dim];
#pragma unroll
        for (int i = 0; i < 4; ++i) {
          const float x = acc[m][nt][i] + bj;
          const float gel = 0.5f * x * (1.0f + erff(x * 0.70710678118654752f));
          const int ci = (m * 16 + rb + i) * CS + dim;
          C[ci] = C[ci] + gel;
        }
      }
  }
  __syncthreads();

  // LN2 -> out (fp32 full slot overwrite): 4 rows per wave
  float* outp = (float*)dout;
#pragma unroll
  for (int tt = 0; tt < 4; ++tt) {
    const int t = w * 4 + tt, tok = tok0 + t;
    float4 v = *reinterpret_cast<float4*>(&C[t * CS + lane * 4]);
    float s = v.x + v.y + v.z + v.w;
#pragma unroll
    for (int o = 32; o; o >>= 1) s += __shfl_xor(s, o);
    const float m = s * (1.f / 256.f);
    const float d0 = v.x - m, d1 = v.y - m, d2 = v.z - m, d3 = v.w - m;
    float s2 = d0 * d0 + d1 * d1 + d2 * d2 + d3 * d3;
#pragma unroll
    for (int o = 32; o; o >>= 1) s2 += __shfl_xor(s2, o);
    const float rs = rsqrtf(s2 * (1.f / 256.f) + 1e-5f);
    if (tok < NTOK) {
      const float4 gg = *reinterpret_cast<const float4*>(&g2[lane * 4]);
      const float4 bb = *reinterpret_cast<const float4*>(&be2[lane * 4]);
      float4 o4;
      o4.x = d0 * rs * gg.x + bb.x; o4.y = d1 * rs * gg.y + bb.y;
      o4.z = d2 * rs * gg.z + bb.z; o4.w = d3 * rs * gg.w + bb.w;
      *reinterpret_cast<float4*>(&outp[(size_t)tok * DM + lane * 4]) = o4;
    }
  }
}

// ---------------- launch ----------------

extern "C" void kernel_launch(void* const* d_in, const int* in_sizes, int n_in,
                              void* d_out, int out_size, void* d_ws, size_t ws_size,
                              hipStream_t stream) {
  const float* tgt    = (const float*)d_in[0];
  const float* qp     = (const float*)d_in[1];
  const float* ref    = (const float*)d_in[2];
  const float* src    = (const float*)d_in[3];
  const float* w_ds   = (const float*)d_in[6];
  const float* b_ds   = (const float*)d_in[7];
  const float* g_ds   = (const float*)d_in[8];
  const float* be_ds  = (const float*)d_in[9];
  const float* w_off  = (const float*)d_in[10];
  const float* b_off  = (const float*)d_in[11];
  const float* w_attn = (const float*)d_in[12];
  const float* b_attn = (const float*)d_in[13];
  const float* w_val  = (const float*)d_in[14];
  const float* b_val  = (const float*)d_in[15];
  const float* w_out  = (const float*)d_in[16];
  const float* b_out  = (const float*)d_in[17];
  const float* w_cs   = (const float*)d_in[18];
  const float* b_cs   = (const float*)d_in[19];
  const float* g1     = (const float*)d_in[20];
  const float* be1    = (const float*)d_in[21];
  const float* w1     = (const float*)d_in[22];
  const float* b1     = (const float*)d_in[23];
  const float* g2     = (const float*)d_in[24];
  const float* be2    = (const float*)d_in[25];

  ushort*   pw   = (ushort*)d_ws;
  float*    b_oc = (float*)((char*)d_ws + B_OC_OFF);
  unsigned* xy_g = (unsigned*)((char*)d_ws + XY_WS_OFF);
  ushort*   aw_g = (ushort*)((char*)d_ws + AW_WS_OFF);
  unsigned char* dout = (unsigned char*)d_out;

  const int gblk = (NTOK + 3) / 4;             // 5627
  hipLaunchKernelGGL(k_prep, dim3(209), dim3(256), 0, stream,
                     w_ds, w_val, w_off, w1, w_attn, w_out, w_cs, b_out, b_cs,
                     pw, b_oc);
  hipLaunchKernelGGL(k_vh, dim3(2 * NBLK32), dim3(512), 0, stream,
                     src, tgt, qp, ref, pw, b_ds, g_ds, be_ds, b_val,
                     b_off, b_attn, xy_g, aw_g, dout);
  hipLaunchKernelGGL(k_gather, dim3(gblk), dim3(256), 0, stream,
                     xy_g, aw_g, dout);
  hipLaunchKernelGGL(k_tail, dim3(NBLK32), dim3(512), 0, stream,
                     tgt, pw, b_oc, g1, be1, b1, g2, be2, dout);
}

// Round 15
// 119.412 us; speedup vs baseline: 6.9778x; 1.0853x over previous
//
#include <hip/hip_runtime.h>
#include <hip/hip_fp16.h>
#include <math.h>

// Problem constants (fixed by setup_inputs)
#define DM    256
#define LQ    11253
#define NTOK  (2*LQ)        // 22506
#define TT2   32            // tokens per block (GEMM kernels)
#define NBLK32 704          // ceil(NTOK/32)
#define AS    264           // ushorts per A/Cb (bf16) LDS row: 256 + 8 pad

typedef __attribute__((ext_vector_type(8))) short bf16x8;
typedef __attribute__((ext_vector_type(4))) float f32x4;

// packed-weight offsets (ushort units)
#define PW_DS  0
#define PW_VAL 65536
#define PW_OFA 131072      // w_off (nt 0..15) ++ w_attn (nt 16..23), 98304 ushorts
#define PW_W1  229376
#define PW_OC  294912      // w_out @ w_cs fused
// ws layout (bytes): pw [0,~721K) | b_oc [860160,861184) | xy [1MiB,12MiB) | aw [12MiB,~17.8MiB)
#define B_OC_OFF  860160u
#define XY_WS_OFF (1u<<20)
#define AW_WS_OFF (12u<<20)
// d_out layout: per token a 1024B slot: ATT bf16 [0,512) | value bf16 [512,1024)

// ---------------- small helpers ----------------

__device__ __forceinline__ ushort f2b(float x) {   // fp32 -> bf16 (RNE)
  union { float f; unsigned u; } c; c.f = x;
  unsigned u = c.u + 0x7fffu + ((c.u >> 16) & 1u);
  return (ushort)(u >> 16);
}
__device__ __forceinline__ float b2f(ushort u) {   // bf16 -> fp32
  union { unsigned u; float f; } c; c.u = ((unsigned)u) << 16; return c.f;
}
__device__ __forceinline__ float blo(unsigned u) {
  union { unsigned u; float f; } c; c.u = u << 16; return c.f;
}
__device__ __forceinline__ float bhi(unsigned u) {
  union { unsigned u; float f; } c; c.u = u & 0xffff0000u; return c.f;
}
__device__ __forceinline__ int clampr(int v) { return min(max(v, 0), NTOK - 1); }

// ------------- k_prep: weight pack (144 blk) + w_oc matmul (64) + b_oc (1) --

__global__ __launch_bounds__(256) void k_prep(
    const float* __restrict__ w_ds, const float* __restrict__ w_val,
    const float* __restrict__ w_off, const float* __restrict__ w1,
    const float* __restrict__ wa,
    const float* __restrict__ w_out, const float* __restrict__ w_cs,
    const float* __restrict__ b_out, const float* __restrict__ b_cs,
    ushort* __restrict__ pw, float* __restrict__ b_oc) {
  __shared__ float rows[4][256];
  const int bid = blockIdx.x, j = threadIdx.x;

  if (bid < 144) {
    const int gid = bid * 256 + j;
    const float* W; int N; size_t obase; int local; int ntAdd;
    if (gid < 4 * 8192) {
      const int wi = gid >> 13; local = gid & 8191; N = 256; ntAdd = 0;
      obase = (wi == 0) ? PW_DS : (wi == 1) ? PW_VAL : (wi == 2) ? PW_OFA : PW_W1;
      W = (wi == 0) ? w_ds : (wi == 1) ? w_val : (wi == 2) ? w_off : w1;
    } else {
      local = gid - 32768; N = 128; obase = PW_OFA; W = wa; ntAdd = 16;
    }
    const int l = local & 63, f = local >> 6;
    const int kt = f & 7, nt = f >> 3;
    const int k0 = kt * 32 + (l >> 4) * 8, col = nt * 16 + (l & 15);
    ushort v[8];
#pragma unroll
    for (int e = 0; e < 8; ++e) v[e] = f2b(W[(size_t)(k0 + e) * N + col]);
    const size_t fout = (size_t)(((nt + ntAdd) * 8 + kt) * 64 + l);
    *reinterpret_cast<uint4*>(&pw[obase + fout * 8]) =
        *reinterpret_cast<const uint4*>(v);
  } else if (bid < 208) {
    const int k0 = (bid - 144) * 4;
#pragma unroll
    for (int rr = 0; rr < 4; ++rr) rows[rr][j] = w_out[(size_t)(k0 + rr) * 256 + j];
    __syncthreads();
    float s[4];
#pragma unroll
    for (int rr = 0; rr < 4; ++rr) s[rr] = 0.f;
    for (int m = 0; m < 256; ++m) {
      const float c = w_cs[(size_t)m * 256 + j];
#pragma unroll
      for (int rr = 0; rr < 4; ++rr) s[rr] = fmaf(rows[rr][m], c, s[rr]);
    }
    const int nt = j >> 4;
#pragma unroll
    for (int rr = 0; rr < 4; ++rr) {
      const int k = k0 + rr;
      const int kt = k >> 5, ln = ((k >> 3) & 3) * 16 + (j & 15), e = k & 7;
      pw[PW_OC + ((size_t)((nt * 8 + kt) * 64 + ln)) * 8 + e] = f2b(s[rr]);
    }
  } else {
    float s = b_cs[j];
    for (int m = 0; m < 256; ++m) s = fmaf(b_out[m], w_cs[(size_t)m * 256 + j], s);
    b_oc[j] = s;
  }
}

// -------- GEMM tile helpers: 512 threads, 8 waves, 32 tokens, B reused x2 ---

template<int NTW>
__device__ __forceinline__ void gemm_tile32(const ushort* __restrict__ A,
                                            const ushort* __restrict__ Bp,
                                            int ntBase, int lane,
                                            f32x4 (&acc)[2][NTW]) {
  const int r = lane & 15, hk = lane >> 4;
  const ushort* arow0 = A + r * AS + hk * 8;
  const ushort* arow1 = A + (r + 16) * AS + hk * 8;
#pragma unroll
  for (int m = 0; m < 2; ++m)
#pragma unroll
    for (int nt = 0; nt < NTW; ++nt) acc[m][nt] = (f32x4){0.f, 0.f, 0.f, 0.f};
#pragma unroll
  for (int kt = 0; kt < 8; ++kt) {
    const bf16x8 a0 = *(const bf16x8*)(arow0 + kt * 32);
    const bf16x8 a1 = *(const bf16x8*)(arow1 + kt * 32);
#pragma unroll
    for (int nt = 0; nt < NTW; ++nt) {
      const bf16x8 b = *(const bf16x8*)(Bp + ((size_t)((ntBase + nt) * 8 + kt) * 64 + lane) * 8);
      acc[0][nt] = __builtin_amdgcn_mfma_f32_16x16x32_bf16(a0, b, acc[0][nt], 0, 0, 0);
      acc[1][nt] = __builtin_amdgcn_mfma_f32_16x16x32_bf16(a1, b, acc[1][nt], 0, 0, 0);
    }
  }
}

// acc + bias -> bf16 staging tile (stride AS)
template<int NTW>
__device__ __forceinline__ void acc_to_cb(const f32x4 (&acc)[2][NTW], ushort* Cb,
                                          const float* __restrict__ bias,
                                          int ntBase, int lane) {
  const int col = lane & 15, rb = (lane >> 4) * 4;
#pragma unroll
  for (int m = 0; m < 2; ++m)
#pragma unroll
    for (int nt = 0; nt < NTW; ++nt) {
      const int dim = (ntBase + nt) * 16 + col;
      const float bj = bias[dim];
#pragma unroll
      for (int i = 0; i < 4; ++i)
        Cb[(m * 16 + rb + i) * AS + dim] = f2b(acc[m][nt][i] + bj);
    }
}

// 8 waves x 4 rows each = 32 rows
template<bool ADD>
__device__ __forceinline__ void load_to_A32(const float* __restrict__ X,
                                            const float* __restrict__ Y,
                                            int tok0, ushort* A, int w, int lane) {
#pragma unroll
  for (int tt = 0; tt < 4; ++tt) {
    const int t = w * 4 + tt, tok = tok0 + t;
    float4 v = make_float4(0.f, 0.f, 0.f, 0.f);
    if (tok < NTOK) {
      v = *reinterpret_cast<const float4*>(&X[(size_t)tok * DM + lane * 4]);
      if (ADD) {
        const float4 y = *reinterpret_cast<const float4*>(&Y[(size_t)tok * DM + lane * 4]);
        v.x += y.x; v.y += y.y; v.z += y.z; v.w += y.w;
      }
    }
    ushort4 b; b.x = f2b(v.x); b.y = f2b(v.y); b.z = f2b(v.z); b.w = f2b(v.w);
    *reinterpret_cast<ushort4*>(&A[t * AS + lane * 4]) = b;
  }
}

// LayerNorm bf16 rows of Cb -> bf16 into A; 8 waves x 4 rows each
__device__ __forceinline__ void ln_cb_to_a32(const ushort* Cb, ushort* A,
                                             const float* __restrict__ g,
                                             const float* __restrict__ be,
                                             int w, int lane) {
#pragma unroll
  for (int tt = 0; tt < 4; ++tt) {
    const int t = w * 4 + tt;
    const ushort4 u4 = *reinterpret_cast<const ushort4*>(&Cb[t * AS + lane * 4]);
    const float v0 = b2f(u4.x), v1 = b2f(u4.y), v2 = b2f(u4.z), v3 = b2f(u4.w);
    float s = v0 + v1 + v2 + v3;
#pragma unroll
    for (int o = 32; o; o >>= 1) s += __shfl_xor(s, o);
    const float m = s * (1.f / 256.f);
    const float d0 = v0 - m, d1 = v1 - m, d2 = v2 - m, d3 = v3 - m;
    float s2 = d0 * d0 + d1 * d1 + d2 * d2 + d3 * d3;
#pragma unroll
    for (int o = 32; o; o >>= 1) s2 += __shfl_xor(s2, o);
    const float rs = rsqrtf(s2 * (1.f / 256.f) + 1e-5f);
    const float4 gg = *reinterpret_cast<const float4*>(&g[lane * 4]);
    const float4 bb = *reinterpret_cast<const float4*>(&be[lane * 4]);
    ushort4 ob;
    ob.x = f2b(d0 * rs * gg.x + bb.x); ob.y = f2b(d1 * rs * gg.y + bb.y);
    ob.z = f2b(d2 * rs * gg.z + bb.z); ob.w = f2b(d3 * rs * gg.w + bb.w);
    *reinterpret_cast<ushort4*>(&A[t * AS + lane * 4]) = ob;
  }
}

// ------------- k_vh: value role (bid even) + head role (bid odd) ------------

__global__ __launch_bounds__(512) void k_vh(
    const float* __restrict__ src, const float* __restrict__ tgt,
    const float* __restrict__ qp, const float* __restrict__ ref,
    const ushort* __restrict__ pw,
    const float* __restrict__ b_ds, const float* __restrict__ g_ds,
    const float* __restrict__ be_ds, const float* __restrict__ b_val,
    const float* __restrict__ b_off, const float* __restrict__ b_attn,
    unsigned* __restrict__ xy_g, ushort* __restrict__ aw_g,
    unsigned char* __restrict__ dout) {
  __shared__ __align__(16) ushort A[TT2 * AS];
  __shared__ __align__(16) ushort Cb[TT2 * AS];
  const int tid = threadIdx.x, w = tid >> 6, lane = tid & 63;
  const int bid = blockIdx.x;
  const int tok0 = (bid >> 1) * TT2;

  if ((bid & 1) == 0) {
    // ================= value role =================
    load_to_A32<false>(src, nullptr, tok0, A, w, lane);
    __syncthreads();
    f32x4 acc[2][2];
    gemm_tile32<2>(A, pw + PW_DS, w * 2, lane, acc);
    acc_to_cb<2>(acc, Cb, b_ds, w * 2, lane);
    __syncthreads();
    ln_cb_to_a32(Cb, A, g_ds, be_ds, w, lane);
    __syncthreads();
    gemm_tile32<2>(A, pw + PW_VAL, w * 2, lane, acc);
    acc_to_cb<2>(acc, Cb, b_val, w * 2, lane);
    __syncthreads();
    // value store: Cb already bf16 -> direct coalesced copy
#pragma unroll
    for (int tt = 0; tt < 4; ++tt) {
      const int t = w * 4 + tt, tok = tok0 + t;
      if (tok < NTOK) {
        const ushort4 b = *reinterpret_cast<const ushort4*>(&Cb[t * AS + lane * 4]);
        *reinterpret_cast<ushort4*>(dout + (size_t)tok * 1024 + 512 + lane * 8) = b;
      }
    }
  } else {
    // ================= head role =================
    load_to_A32<true>(tgt, qp, tok0, A, w, lane);
    __syncthreads();

    f32x4 acc[2][3];
    gemm_tile32<3>(A, pw + PW_OFA, w * 3, lane, acc);
    __syncthreads();   // all waves done reading A (q) -> logits may overwrite A
    // offsets (g<16) -> Cb bf16; logits (g>=16) -> A[row][adim] bf16
    {
      const int col = lane & 15, rb = (lane >> 4) * 4;
#pragma unroll
      for (int m = 0; m < 2; ++m)
#pragma unroll
        for (int j = 0; j < 3; ++j) {
          const int g = w * 3 + j;
          if (g < 16) {
            const int dim = g * 16 + col;
            const float bj = b_off[dim];
#pragma unroll
            for (int i = 0; i < 4; ++i)
              Cb[(m * 16 + rb + i) * AS + dim] = f2b(acc[m][j][i] + bj);
          } else {
            const int adim = (g - 16) * 16 + col;
            const float bj = b_attn[adim];
#pragma unroll
            for (int i = 0; i < 4; ++i)
              A[(m * 16 + rb + i) * AS + adim] = f2b(acc[m][j][i] + bj);
          }
        }
    }
    __syncthreads();

    // softmax over 16 per (token, head): 256 of 512 threads; bf16 in-place
    if (tid < TT2 * 8) {
      const int t = tid >> 3, h = tid & 7;
      ushort* a = &A[t * AS + h * 16];
      float v[16];
#pragma unroll
      for (int i = 0; i < 16; ++i) v[i] = b2f(a[i]);
      float m = v[0];
#pragma unroll
      for (int i = 1; i < 16; ++i) m = fmaxf(m, v[i]);
      float s = 0.f, e[16];
#pragma unroll
      for (int i = 0; i < 16; ++i) { e[i] = expf(v[i] - m); s += e[i]; }
      const float inv = 1.0f / s;
#pragma unroll
      for (int i = 0; i < 16; ++i) a[i] = f2b(e[i] * inv);
    }
    __syncthreads();

    // descriptors: thread -> (quarter = tid>>7, pt = tid&127); 8 tokens each
    {
      const int quarter = tid >> 7, pt = tid & 127;
      const int l = (pt >> 2) & 3;
      const int Wl = (l == 0) ? 92 : (l == 1) ? 46 : (l == 2) ? 23 : 12;
      const float fW = (float)Wl;
#pragma unroll
      for (int it = 0; it < 8; ++it) {
        const int tl = quarter * 8 + it;
        const int tok = tok0 + tl;
        const int tokc = (tok < NTOK) ? tok : (NTOK - 1);
        const float refx = ref[(size_t)tokc * 8 + l * 2 + 0];
        const float refy = ref[(size_t)tokc * 8 + l * 2 + 1];
        const float vmask = (tok < NTOK) ? 1.f : 0.f;
        const float ox = b2f(Cb[tl * AS + pt * 2 + 0]);
        const float oy = b2f(Cb[tl * AS + pt * 2 + 1]);
        const float aw = b2f(A[tl * AS + pt]) * vmask;
        float x = fmaf(refx, fW, ox) - 0.5f;
        float y = fmaf(refy, fW, oy) - 0.5f;
        x = fminf(fmaxf(x, -1.f), 126.9f);
        y = fminf(fmaxf(y, -1.f), 126.9f);
        const unsigned ux = (unsigned)(int)rintf((x + 1.f) * 512.f);
        const unsigned uy = (unsigned)(int)rintf((y + 1.f) * 512.f);
        xy_g[(size_t)tok * 128 + pt] = ux | (uy << 16);
        aw_g[(size_t)tok * 128 + pt] = __half_as_ushort(__float2half_rn(aw));
      }
    }
  }
}

// ------------- kernel 3: gather — R9-exact FROZEN (proven 55.5 µs optimum) --
// Per-lane inline descriptor math intentionally kept: the VALU chain paces the
// load stream so the per-(token,level) 2x2 pixel clusters stay L2-resident.
// FOUR experiments (R5, R8, R10, R13) proved ANY perturbation of this issue
// structure (slim math, wider payloads, fewer waves) thrashes L2 (FETCH
// 55MB -> 97MB-1.2GB) and regresses 1.2-13x. Do not touch this kernel.

__global__ __launch_bounds__(256, 6) void k_gather(
    const unsigned* __restrict__ xy_g, const ushort* __restrict__ aw_g,
    unsigned char* __restrict__ dout) {
  __shared__ unsigned sxy[4 * 128];
  __shared__ ushort   saw[4 * 128];
  const int tid = threadIdx.x;

  // bijective XCD swizzle: gblk = 5627 = 8*703 + 3  (q=703, r=3; m204 variant)
  const int bid = blockIdx.x;
  const int xcd = bid & 7, pos = bid >> 3;
  const int swz = (xcd < 3) ? (xcd * 704 + pos) : (3 * 704 + (xcd - 3) * 703 + pos);
  const int tb0 = swz * 4;

  sxy[tid]       = xy_g[(size_t)tb0 * 128 + tid];
  sxy[tid + 256] = xy_g[(size_t)tb0 * 128 + tid + 256];
  saw[tid]       = aw_g[(size_t)tb0 * 128 + tid];
  saw[tid + 256] = aw_g[(size_t)tb0 * 128 + tid + 256];
  __syncthreads();

  const int tl = tid >> 6, h = (tid >> 3) & 7, sl = tid & 7;
  const int tok = tb0 + tl;
  const int bb = (tok >= LQ) ? LQ : 0;
  const int col8 = h * 16 + sl * 2;
  const unsigned char* __restrict__ vb = dout;

  float o0 = 0.f, o1 = 0.f, o2 = 0.f, o3 = 0.f;
#pragma unroll
  for (int l = 0; l < 4; ++l) {
    const int Wl  = (l == 0) ? 92 : (l == 1) ? 46 : (l == 2) ? 23 : 12;
    const int lsi = (l == 0) ? 0  : (l == 1) ? 8464 : (l == 2) ? 10580 : 11109;
    const int rbas = bb + lsi;
#pragma unroll
    for (int p = 0; p < 4; ++p) {
      const int pt = l * 4 + p;
      const unsigned uxy = sxy[tl * 128 + h * 16 + pt];
      const float aw = __half2float(__ushort_as_half(saw[tl * 128 + h * 16 + pt]));
      const float x = (float)(uxy & 0xffffu) * (1.f / 512.f) - 1.f;
      const float y = (float)(uxy >> 16)     * (1.f / 512.f) - 1.f;
      const float x0f = floorf(x), y0f = floorf(y);
      const int x0 = (int)x0f, y0 = (int)y0f;
      const float fx = x - x0f, fy = y - y0f;
      const float gx = 1.f - fx, gy = 1.f - fy;
      const float wx0 = ((x0 >= 0) & (x0 < Wl)) ? gx : 0.f;
      const float wx1 = (x0 < Wl - 1) ? fx : 0.f;
      const float wy0 = (((y0 >= 0) & (y0 < Wl)) ? gy : 0.f) * aw;
      const float wy1 = ((y0 < Wl - 1) ? fy : 0.f) * aw;
      const float w00 = wx0 * wy0, w10 = wx1 * wy0;
      const float w01 = wx0 * wy1, w11 = wx1 * wy1;
      const int base = rbas + y0 * Wl + x0;
      const int r00 = clampr(base),      r10 = clampr(base + 1);
      const int r01 = clampr(base + Wl), r11 = clampr(base + Wl + 1);
      const uint2 u00 = *(const uint2*)(vb + (size_t)r00 * 1024 + 512 + col8 * 4);
      const uint2 u10 = *(const uint2*)(vb + (size_t)r10 * 1024 + 512 + col8 * 4);
      const uint2 u01 = *(const uint2*)(vb + (size_t)r01 * 1024 + 512 + col8 * 4);
      const uint2 u11 = *(const uint2*)(vb + (size_t)r11 * 1024 + 512 + col8 * 4);
      o0 = fmaf(w00, blo(u00.x), o0); o1 = fmaf(w00, bhi(u00.x), o1);
      o2 = fmaf(w00, blo(u00.y), o2); o3 = fmaf(w00, bhi(u00.y), o3);
      o0 = fmaf(w10, blo(u10.x), o0); o1 = fmaf(w10, bhi(u10.x), o1);
      o2 = fmaf(w10, blo(u10.y), o2); o3 = fmaf(w10, bhi(u10.y), o3);
      o0 = fmaf(w01, blo(u01.x), o0); o1 = fmaf(w01, bhi(u01.x), o1);
      o2 = fmaf(w01, blo(u01.y), o2); o3 = fmaf(w01, bhi(u01.y), o3);
      o0 = fmaf(w11, blo(u11.x), o0); o1 = fmaf(w11, bhi(u11.x), o1);
      o2 = fmaf(w11, blo(u11.y), o2); o3 = fmaf(w11, bhi(u11.y), o3);
    }
  }
  if (tok < NTOK) {
    const unsigned lo = (unsigned)f2b(o0) | ((unsigned)f2b(o1) << 16);
    const unsigned hi = (unsigned)f2b(o2) | ((unsigned)f2b(o3) << 16);
    uint2 st; st.x = lo; st.y = hi;
    *(uint2*)(dout + (size_t)tok * 1024 + col8 * 4) = st;
  }
}

// ------------- kernel 4: tail = ATT@w_oc (+tgt, LN1) @w1 (GELU+res, LN2) ----

__global__ __launch_bounds__(512) void k_tail(
    const float* __restrict__ tgt, const ushort* __restrict__ pw,
    const float* __restrict__ b_oc,
    const float* __restrict__ g1, const float* __restrict__ be1,
    const float* __restrict__ b1,
    const float* __restrict__ g2, const float* __restrict__ be2,
    unsigned char* __restrict__ dout) {
  __shared__ __align__(16) ushort A[TT2 * AS];
  __shared__ __align__(16) ushort Cb[TT2 * AS];
  const int tid = threadIdx.x, w = tid >> 6, lane = tid & 63;
  const int tok0 = blockIdx.x * TT2;

  // load ATT (bf16) rows from our own d_out slots: 4 rows per wave
#pragma unroll
  for (int tt = 0; tt < 4; ++tt) {
    const int t = w * 4 + tt, tok = tok0 + t;
    ushort4 b = make_ushort4(0, 0, 0, 0);
    if (tok < NTOK)
      b = *reinterpret_cast<const ushort4*>(dout + (size_t)tok * 1024 + lane * 8);
    *reinterpret_cast<ushort4*>(&A[t * AS + lane * 4]) = b;
  }
  __syncthreads();

  f32x4 acc[2][2];
  // t2 = ATT @ w_oc + b_oc   (fused w_out@w_cs) -> Cb bf16
  gemm_tile32<2>(A, pw + PW_OC, w * 2, lane, acc);
  acc_to_cb<2>(acc, Cb, b_oc, w * 2, lane);
  __syncthreads();

  // LN1 over (t2 + tgt): coalesced tgt read; t -> A (GEMM input) and Cb (resid)
#pragma unroll
  for (int tt = 0; tt < 4; ++tt) {
    const int t = w * 4 + tt, tok = tok0 + t;
    const ushort4 u4 = *reinterpret_cast<const ushort4*>(&Cb[t * AS + lane * 4]);
    float v0 = b2f(u4.x), v1 = b2f(u4.y), v2 = b2f(u4.z), v3 = b2f(u4.w);
    if (tok < NTOK) {
      const float4 r = *reinterpret_cast<const float4*>(&tgt[(size_t)tok * DM + lane * 4]);
      v0 += r.x; v1 += r.y; v2 += r.z; v3 += r.w;
    }
    float s = v0 + v1 + v2 + v3;
#pragma unroll
    for (int o = 32; o; o >>= 1) s += __shfl_xor(s, o);
    const float m = s * (1.f / 256.f);
    const float d0 = v0 - m, d1 = v1 - m, d2 = v2 - m, d3 = v3 - m;
    float s2 = d0 * d0 + d1 * d1 + d2 * d2 + d3 * d3;
#pragma unroll
    for (int o = 32; o; o >>= 1) s2 += __shfl_xor(s2, o);
    const float rs = rsqrtf(s2 * (1.f / 256.f) + 1e-5f);
    const float4 gg = *reinterpret_cast<const float4*>(&g1[lane * 4]);
    const float4 bb = *reinterpret_cast<const float4*>(&be1[lane * 4]);
    ushort4 ob;
    ob.x = f2b(d0 * rs * gg.x + bb.x); ob.y = f2b(d1 * rs * gg.y + bb.y);
    ob.z = f2b(d2 * rs * gg.z + bb.z); ob.w = f2b(d3 * rs * gg.w + bb.w);
    *reinterpret_cast<ushort4*>(&A[t * AS + lane * 4]) = ob;
    *reinterpret_cast<ushort4*>(&Cb[t * AS + lane * 4]) = ob;
  }
  __syncthreads();

  // u = gelu(t @ w1 + b1); y = t + u (in-place on Cb, bf16)
  gemm_tile32<2>(A, pw + PW_W1, w * 2, lane, acc);
  {
    const int col = lane & 15, rb = (lane >> 4) * 4;
#pragma unroll
    for (int m = 0; m < 2; ++m)
#pragma unroll
      for (int nt = 0; nt < 2; ++nt) {
        const int dim = (w * 2 + nt) * 16 + col;
        const float bj = b1[dim];
#pragma unroll
        for (int i = 0; i < 4; ++i) {
          const float x = acc[m][nt][i] + bj;
          const float gel = 0.5f * x * (1.0f + erff(x * 0.70710678118654752f));
          const int ci = (m * 16 + rb + i) * AS + dim;
          Cb[ci] = f2b(b2f(Cb[ci]) + gel);
        }
      }
  }
  __syncthreads();

  // LN2 -> out (fp32 full slot overwrite): 4 rows per wave
  float* outp = (float*)dout;
#pragma unroll
  for (int tt = 0; tt < 4; ++tt) {
    const int t = w * 4 + tt, tok = tok0 + t;
    const ushort4 u4 = *reinterpret_cast<const ushort4*>(&Cb[t * AS + lane * 4]);
    const float v0 = b2f(u4.x), v1 = b2f(u4.y), v2 = b2f(u4.z), v3 = b2f(u4.w);
    float s = v0 + v1 + v2 + v3;
#pragma unroll
    for (int o = 32; o; o >>= 1) s += __shfl_xor(s, o);
    const float m = s * (1.f / 256.f);
    const float d0 = v0 - m, d1 = v1 - m, d2 = v2 - m, d3 = v3 - m;
    float s2 = d0 * d0 + d1 * d1 + d2 * d2 + d3 * d3;
#pragma unroll
    for (int o = 32; o; o >>= 1) s2 += __shfl_xor(s2, o);
    const float rs = rsqrtf(s2 * (1.f / 256.f) + 1e-5f);
    if (tok < NTOK) {
      const float4 gg = *reinterpret_cast<const float4*>(&g2[lane * 4]);
      const float4 bb = *reinterpret_cast<const float4*>(&be2[lane * 4]);
      float4 o4;
      o4.x = d0 * rs * gg.x + bb.x; o4.y = d1 * rs * gg.y + bb.y;
      o4.z = d2 * rs * gg.z + bb.z; o4.w = d3 * rs * gg.w + bb.w;
      *reinterpret_cast<float4*>(&outp[(size_t)tok * DM + lane * 4]) = o4;
    }
  }
}

// ---------------- launch ----------------

extern "C" void kernel_launch(void* const* d_in, const int* in_sizes, int n_in,
                              void* d_out, int out_size, void* d_ws, size_t ws_size,
                              hipStream_t stream) {
  const float* tgt    = (const float*)d_in[0];
  const float* qp     = (const float*)d_in[1];
  const float* ref    = (const float*)d_in[2];
  const float* src    = (const float*)d_in[3];
  const float* w_ds   = (const float*)d_in[6];
  const float* b_ds   = (const float*)d_in[7];
  const float* g_ds   = (const float*)d_in[8];
  const float* be_ds  = (const float*)d_in[9];
  const float* w_off  = (const float*)d_in[10];
  const float* b_off  = (const float*)d_in[11];
  const float* w_attn = (const float*)d_in[12];
  const float* b_attn = (const float*)d_in[13];
  const float* w_val  = (const float*)d_in[14];
  const float* b_val  = (const float*)d_in[15];
  const float* w_out  = (const float*)d_in[16];
  const float* b_out  = (const float*)d_in[17];
  const float* w_cs   = (const float*)d_in[18];
  const float* b_cs   = (const float*)d_in[19];
  const float* g1     = (const float*)d_in[20];
  const float* be1    = (const float*)d_in[21];
  const float* w1     = (const float*)d_in[22];
  const float* b1     = (const float*)d_in[23];
  const float* g2     = (const float*)d_in[24];
  const float* be2    = (const float*)d_in[25];

  ushort*   pw   = (ushort*)d_ws;
  float*    b_oc = (float*)((char*)d_ws + B_OC_OFF);
  unsigned* xy_g = (unsigned*)((char*)d_ws + XY_WS_OFF);
  ushort*   aw_g = (ushort*)((char*)d_ws + AW_WS_OFF);
  unsigned char* dout = (unsigned char*)d_out;

  const int gblk = (NTOK + 3) / 4;             // 5627
  hipLaunchKernelGGL(k_prep, dim3(209), dim3(256), 0, stream,
                     w_ds, w_val, w_off, w1, w_attn, w_out, w_cs, b_out, b_cs,
                     pw, b_oc);
  hipLaunchKernelGGL(k_vh, dim3(2 * NBLK32), dim3(512), 0, stream,
                     src, tgt, qp, ref, pw, b_ds, g_ds, be_ds, b_val,
                     b_off, b_attn, xy_g, aw_g, dout);
  hipLaunchKernelGGL(k_gather, dim3(gblk), dim3(256), 0, stream,
                     xy_g, aw_g, dout);
  hipLaunchKernelGGL(k_tail, dim3(NBLK32), dim3(512), 0, stream,
                     tgt, pw, b_oc, g1, be1, b1, g2, be2, dout);
}